// Round 4
// baseline (181.518 us; speedup 1.0000x reference)
//
#include <hip/hip_runtime.h>
#include <math.h>

#define D_MODEL 1024
#define T_SEQ   2048
#define NBATCH  4
#define NROWS   (NBATCH * T_SEQ)          // 8192
#define NOUT    64                        // 32 q + 32 k

#define XLD  1036  // xlds row stride (floats): 1024 + 12; 1036 mod 32 = 12 ->
                   // a-operand ds_read_b32 lane pattern (16 rows x 4 ak) is 2-way = free

typedef double v4df __attribute__((ext_vector_type(4)));

// ---------- top-4 helpers: total order = (value desc, index asc) ----------
__device__ __forceinline__ bool key_gt(float av, int ai, float bv, int bi) {
    return (av > bv) || (av == bv && ai < bi);
}

__device__ __forceinline__ void cmpswap(float& v0, int& i0, float& v1, int& i1) {
    bool sw = key_gt(v1, i1, v0, i0);
    float nv0 = sw ? v1 : v0, nv1 = sw ? v0 : v1;
    int   ni0 = sw ? i1 : i0, ni1 = sw ? i0 : i1;
    v0 = nv0; v1 = nv1; i0 = ni0; i1 = ni1;
}

// merge sorted-desc a[4] with sorted-desc b[4] -> top4 of union into a (bitonic)
__device__ __forceinline__ void merge4(float (&a)[4], int (&ai)[4],
                                       float b0, int j0, float b1, int j1,
                                       float b2, int j2, float b3, int j3) {
    if (!key_gt(a[0], ai[0], b3, j3)) { a[0] = b3; ai[0] = j3; }
    if (!key_gt(a[1], ai[1], b2, j2)) { a[1] = b2; ai[1] = j2; }
    if (!key_gt(a[2], ai[2], b1, j1)) { a[2] = b1; ai[2] = j1; }
    if (!key_gt(a[3], ai[3], b0, j0)) { a[3] = b0; ai[3] = j0; }
    cmpswap(a[0], ai[0], a[2], ai[2]);
    cmpswap(a[1], ai[1], a[3], ai[3]);
    cmpswap(a[0], ai[0], a[1], ai[1]);
    cmpswap(a[2], ai[2], a[3], ai[3]);
}

// insert candidate (v, idx) into sorted-desc top4; strict > keeps earlier index on ties
__device__ __forceinline__ void insert4(float (&tv)[4], int (&tix)[4], float v, int idx) {
    if (v > tv[3]) {
        bool g0 = v > tv[0], g1 = v > tv[1], g2 = v > tv[2];
        float n0 = g0 ? v : tv[0];
        int   m0 = g0 ? idx : tix[0];
        float n1 = g1 ? (g0 ? tv[0] : v) : tv[1];
        int   m1 = g1 ? (g0 ? tix[0] : idx) : tix[1];
        float n2 = g2 ? (g1 ? tv[1] : v) : tv[2];
        int   m2 = g2 ? (g1 ? tix[1] : idx) : tix[2];
        float n3 = g2 ? tv[2] : v;
        int   m3 = g2 ? tix[2] : idx;
        tv[0] = n0; tv[1] = n1; tv[2] = n2; tv[3] = n3;
        tix[0] = m0; tix[1] = m1; tix[2] = m2; tix[3] = m3;
    }
}

// ---------- probe body: f64 MFMA fragment layout, run by one 256-thr block ----------
// tab layout (ints): [0]=flag, [1..64]=am, [65..128]=ak, [129..192]=bk,
//                    [193..256]=bn, [257..512]=dm[lane][4], [513..768]=dn[lane][4]
__device__ void run_probe(int tid, int* __restrict__ tab)
{
    __shared__ double Aref[16][4];
    __shared__ double Bref[4][16];
    __shared__ double Dref[16][16];

    const int lane = tid;   // only tid<64 used for lane-specific work
    if (tid < 64) {
        const int m = lane & 15, k = lane >> 4;
        Aref[m][k] = (double)(1 + m * 4 + k);     // distinct, asymmetric
        Bref[k][m] = (double)(1 + k * 16 + m);
    }
    __syncthreads();
    {   // 256 threads: one D element each
        const int e = tid;
        const int m = e >> 4, n = e & 15;
        double s = 0.0;
        for (int k = 0; k < 4; ++k) s += Aref[m][k] * Bref[k][n];
        Dref[m][n] = s;   // exact integer-valued f64
    }
    __syncthreads();

    if (tid >= 64) return;   // wave 0 does the hypothesis search

    int found = -1;
    for (int h = 0; h < 16; ++h) {
        if (found >= 0) break;
        const int fa = h & 1, fb = (h >> 1) & 1, fd = h >> 2;
        const int am = fa ? (lane >> 2) : (lane & 15);
        const int ak = fa ? (lane & 3)  : (lane >> 4);
        const int bn = fb ? (lane >> 2) : (lane & 15);
        const int bk = fb ? (lane & 3)  : (lane >> 4);
        v4df c = {0.0, 0.0, 0.0, 0.0};
        c = __builtin_amdgcn_mfma_f64_16x16x4f64(Aref[am][ak], Bref[bk][bn], c, 0, 0, 0);
        bool ok = true;
        #pragma unroll
        for (int i = 0; i < 4; ++i) {
            int dm, dn;
            if (fd == 0)      { dm = 4 * (lane >> 4) + i; dn = lane & 15; }
            else if (fd == 1) { dn = 4 * (lane >> 4) + i; dm = lane & 15; }
            else if (fd == 2) { dm = (lane >> 4) + 4 * i; dn = lane & 15; }
            else              { dn = (lane >> 4) + 4 * i; dm = lane & 15; }
            if (c[i] != Dref[dm][dn]) ok = false;
        }
        if (__all(ok)) found = h;
    }

    const int fa = (found >= 0) ? (found & 1) : 0;
    const int fb = (found >= 0) ? ((found >> 1) & 1) : 0;
    const int fd = (found >= 0) ? (found >> 2) : 0;
    tab[1   + lane] = fa ? (lane >> 2) : (lane & 15);
    tab[65  + lane] = fa ? (lane & 3)  : (lane >> 4);
    tab[129 + lane] = fb ? (lane & 3)  : (lane >> 4);
    tab[193 + lane] = fb ? (lane >> 2) : (lane & 15);
    #pragma unroll
    for (int i = 0; i < 4; ++i) {
        int dm, dn;
        if (fd == 0)      { dm = 4 * (lane >> 4) + i; dn = lane & 15; }
        else if (fd == 1) { dn = 4 * (lane >> 4) + i; dm = lane & 15; }
        else if (fd == 2) { dm = (lane >> 4) + 4 * i; dn = lane & 15; }
        else              { dn = (lane >> 4) + 4 * i; dm = lane & 15; }
        tab[257 + lane * 4 + i] = dm;
        tab[513 + lane * 4 + i] = dn;
    }
    if (lane == 0) tab[0] = found;
}

// ---------- Phase 1: W convert (all blocks) + probe (block 0) ----------
__global__ __launch_bounds__(256) void wprep_probe(
    const float* __restrict__ Wq, const float* __restrict__ Wk,
    double* __restrict__ Wdt, int* __restrict__ tab)
{
    const int tid = threadIdx.x;
    const int idx = blockIdx.x * 256 + tid;   // 65536 total
    const int o = idx & 63;
    const int d = idx >> 6;
    float v = (o < 32) ? Wq[(size_t)o * D_MODEL + d]
                       : Wk[(size_t)(o - 32) * D_MODEL + d];
    Wdt[(size_t)d * 64 + o] = (double)v;

    if (blockIdx.x == 0) run_probe(tid, tab); // full-block barriers inside
}

// ---------- Phase 2: projection via f64 MFMA, d-split wave pairs ----------
// grid 512 (= 8192 rows / 16), block 512 (8 waves). Wave pair (og, half):
// og = wav>>1 owns out-tile og*16; half = wav&1 owns d in [half*512, half*512+512).
// Round-3 lesson: a single 128-long dependent MFMA chain left the f64 matrix
// pipe starved (~3x over the 13.7us MFMA floor). Now 4 INDEPENDENT chains of
// 32 (d-blocked, each ascending), combined (c0+c1)+(c2+c3) in fixed order —
// f64 regrouping error ~2^-45 relative, invisible after the single f32 round.
__global__ __launch_bounds__(512) void proj_mfma(
    const float* __restrict__ x, const double* __restrict__ Wdt,
    const float* __restrict__ bq, const float* __restrict__ bk_,
    const int* __restrict__ tab,
    float* __restrict__ Qt, float* __restrict__ Kt)
{
    __shared__ float  xlds[16 * XLD];     // 66304 B
    __shared__ double comb[4][64][4];     // 8192 B

    const int tid  = threadIdx.x;
    const int lane = tid & 63;
    const int wav  = tid >> 6;                                      // 0..7
    const int og   = __builtin_amdgcn_readfirstlane(wav >> 1);      // 0..3
    const int half = __builtin_amdgcn_readfirstlane(wav & 1);       // 0..1
    const int row0 = blockIdx.x * 16;
    const int dbase = half * 512;

    const int flag = tab[0];
    const int am  = tab[1   + lane];
    const int ak  = tab[65  + lane];
    const int bkk = tab[129 + lane];
    const int bn  = tab[193 + lane];

    const double* wcol = Wdt + og * 16;   // + d*64 + bn

    // stage x: 16 rows x 1024 d = 4096 float4, 8 per thread, coalesced
    #pragma unroll
    for (int j = 0; j < 8; ++j) {
        const int f  = j * 512 + tid;
        const int r  = f >> 8;            // 0..15
        const int c4 = f & 255;           // float4 within row
        float4 v = *reinterpret_cast<const float4*>(
            x + (size_t)(row0 + r) * D_MODEL + c4 * 4);
        *reinterpret_cast<float4*>(&xlds[r * XLD + c4 * 4]) = v;
    }
    __syncthreads();

    v4df acc = {0.0, 0.0, 0.0, 0.0};

    if (flag >= 0) {
        // 4 independent chains over this half's 512 d: chain c covers
        // d in [dbase + c*128, dbase + (c+1)*128), k ascending within chain.
        v4df c0 = {0.0, 0.0, 0.0, 0.0};
        v4df c1 = {0.0, 0.0, 0.0, 0.0};
        v4df c2 = {0.0, 0.0, 0.0, 0.0};
        v4df c3 = {0.0, 0.0, 0.0, 0.0};
        const float*  ap = &xlds[am * XLD + dbase + ak];
        const double* bp = wcol + ((size_t)(dbase + bkk)) * 64 + bn;   // + kk*256
        #pragma unroll 8
        for (int kk = 0; kk < 32; ++kk) {
            double aA = (double)ap[kk * 4];
            double aB = (double)ap[128 + kk * 4];
            double aC = (double)ap[256 + kk * 4];
            double aD = (double)ap[384 + kk * 4];
            double bA = bp[(size_t)kk * 256];
            double bB = bp[(size_t)(kk + 32) * 256];
            double bC = bp[(size_t)(kk + 64) * 256];
            double bD = bp[(size_t)(kk + 96) * 256];
            c0 = __builtin_amdgcn_mfma_f64_16x16x4f64(aA, bA, c0, 0, 0, 0);
            c1 = __builtin_amdgcn_mfma_f64_16x16x4f64(aB, bB, c1, 0, 0, 0);
            c2 = __builtin_amdgcn_mfma_f64_16x16x4f64(aC, bC, c2, 0, 0, 0);
            c3 = __builtin_amdgcn_mfma_f64_16x16x4f64(aD, bD, c3, 0, 0, 0);
        }
        acc = (c0 + c1) + (c2 + c3);   // fixed combine order -> deterministic
    } else {
        // scalar f64 fallback: out n = lane&15, rows 4*(lane>>4)+i
        const int n  = lane & 15;
        const int r4 = (lane >> 4) * 4;
        for (int dd = 0; dd < 512; ++dd) {
            const int d = dbase + dd;
            double wv = wcol[(size_t)d * 64 + n];
            #pragma unroll
            for (int i = 0; i < 4; ++i)
                acc[i] = fma((double)xlds[(r4 + i) * XLD + d], wv, acc[i]);
        }
    }

    if (half == 1) {
        #pragma unroll
        for (int i = 0; i < 4; ++i) comb[og][lane][i] = acc[i];
    }
    __syncthreads();

    if (half == 0) {
        // total = low + high (fixed order -> deterministic), + bias, store
        #pragma unroll
        for (int i = 0; i < 4; ++i) {
            const double tot = acc[i] + comb[og][lane][i];
            const int dmv = tab[257 + lane * 4 + i];
            const int dnv = tab[513 + lane * 4 + i];
            const int out = og * 16 + dnv;
            const int row = row0 + dmv;
            const int bb  = row >> 11, t = row & 2047;
            const double bias = (out < 32) ? (double)bq[out] : (double)bk_[out - 32];
            const float v = (float)(tot + bias);
            if (out < 32) Qt[((size_t)bb * 32 + out) * T_SEQ + t] = v;
            else          Kt[((size_t)bb * 32 + (out - 32)) * T_SEQ + t] = v;
        }
    }
}

// ---------- Phase 3: sim + top-4 + gather, L2-direct, spill-free ----------
// Round-3 lesson: 4t x 8s micro-tile (acc 32 + tv/tix 32 regs) spilled at
// VGPR_Count 60 -> scratch traffic inflated VALU 2.7x. Now 2t x 8s:
// acc[2][8]=16 + tv/tix[2][4]=16, ~45 live regs -> no spill, 8 waves/EU cap.
// grid 2048 = b(4) x ttile(512 x 4 rows); block 256 (4 waves) -> 8 blocks/CU,
// spare blocks overlap gather tails. Kt (1 MB total) is per-XCD-L2-resident.
// FMA order (i ascending) identical to prior rounds -> bit-identical sims.
__global__ __launch_bounds__(256, 4) void sim_topk_gather(
    const float* __restrict__ x,
    const float* __restrict__ Qt, const float* __restrict__ Kt,
    float* __restrict__ out)
{
    __shared__ float cV[4][4][4];
    __shared__ int   cI[4][4][4];
    __shared__ int   topIdx[4][4];

    const int tid  = threadIdx.x;
    const int lane = tid & 63;
    const int wav  = tid >> 6;            // 0..3
    const int tt   = blockIdx.x & 511;
    const int b    = blockIdx.x >> 9;
    const int tblk = tt * 4;
    const int tg   = tid & 1;             // 2 t-groups x 2 rows = 4 rows
    const int sg   = tid >> 1;            // 128 s-groups x 8 s (x2 sweeps) = 2048 s

    const float* QtB = Qt + (size_t)b * 32 * T_SEQ;
    const float* KtB = Kt + (size_t)b * 32 * T_SEQ;
    const int trow0 = tblk + tg * 2;

    float tv[2][4]; int tix[2][4];
    #pragma unroll
    for (int r = 0; r < 2; ++r)
        #pragma unroll
        for (int j = 0; j < 4; ++j) { tv[r][j] = -INFINITY; tix[r][j] = 0x7fffffff; }

    #pragma unroll
    for (int sweep = 0; sweep < 2; ++sweep) {
        const int s0 = sweep * 1024 + sg * 8;

        float acc[2][8];
        #pragma unroll
        for (int r = 0; r < 2; ++r)
            #pragma unroll
            for (int c = 0; c < 8; ++c) acc[r][c] = 0.f;

        #pragma unroll 4
        for (int i = 0; i < 32; ++i) {
            float2 qv  = *reinterpret_cast<const float2*>(QtB + (size_t)i * T_SEQ + trow0);
            float4 kv0 = *reinterpret_cast<const float4*>(KtB + (size_t)i * T_SEQ + s0);
            float4 kv1 = *reinterpret_cast<const float4*>(KtB + (size_t)i * T_SEQ + s0 + 4);
            const float qa[2] = {qv.x, qv.y};
            const float ka[8] = {kv0.x, kv0.y, kv0.z, kv0.w, kv1.x, kv1.y, kv1.z, kv1.w};
            #pragma unroll
            for (int r = 0; r < 2; ++r)
                #pragma unroll
                for (int c = 0; c < 8; ++c)
                    acc[r][c] = fmaf(qa[r], ka[c], acc[r][c]);
        }

        #pragma unroll
        for (int c = 0; c < 8; ++c)
            #pragma unroll
            for (int r = 0; r < 2; ++r)
                insert4(tv[r], tix[r], acc[r][c], s0 + c);
    }

    // in-wave butterfly: masks 2..32 preserve t-group (lane&1)
    #pragma unroll
    for (int m = 2; m <= 32; m <<= 1) {
        #pragma unroll
        for (int r = 0; r < 2; ++r) {
            float b0 = __shfl_xor(tv[r][0], m, 64);
            float b1 = __shfl_xor(tv[r][1], m, 64);
            float b2 = __shfl_xor(tv[r][2], m, 64);
            float b3 = __shfl_xor(tv[r][3], m, 64);
            int   j0 = __shfl_xor(tix[r][0], m, 64);
            int   j1 = __shfl_xor(tix[r][1], m, 64);
            int   j2 = __shfl_xor(tix[r][2], m, 64);
            int   j3 = __shfl_xor(tix[r][3], m, 64);
            merge4(tv[r], tix[r], b0, j0, b1, j1, b2, j2, b3, j3);
        }
    }

    if (lane < 2) {    // lane == tg; rows lane*2+r
        #pragma unroll
        for (int r = 0; r < 2; ++r)
            #pragma unroll
            for (int j = 0; j < 4; ++j) {
                cV[wav][lane * 2 + r][j] = tv[r][j];
                cI[wav][lane * 2 + r][j] = tix[r][j];
            }
    }
    __syncthreads();

    // cross-wave merge (4 waves) -> final top-4 per row (4 rows)
    if (tid < 4) {
        float mv[4]; int mi[4];
        #pragma unroll
        for (int j = 0; j < 4; ++j) { mv[j] = cV[0][tid][j]; mi[j] = cI[0][tid][j]; }
        #pragma unroll
        for (int w = 1; w < 4; ++w)
            merge4(mv, mi,
                   cV[w][tid][0], cI[w][tid][0],
                   cV[w][tid][1], cI[w][tid][1],
                   cV[w][tid][2], cI[w][tid][2],
                   cV[w][tid][3], cI[w][tid][3]);
        #pragma unroll
        for (int j = 0; j < 4; ++j) topIdx[tid][j] = mi[j];
    }
    __syncthreads();

    // gather + mean for this block's 4 rows; 256 threads cover the 1024-float row
    const float* xb = x + (size_t)b * T_SEQ * D_MODEL;
    float* ob = out + ((size_t)b * T_SEQ + tblk) * D_MODEL;
    #pragma unroll 4
    for (int r = 0; r < 4; ++r) {
        const int i0 = topIdx[r][0], i1 = topIdx[r][1], i2 = topIdx[r][2], i3 = topIdx[r][3];
        float4 a0 = *(reinterpret_cast<const float4*>(xb + (size_t)i0 * D_MODEL) + tid);
        float4 a1 = *(reinterpret_cast<const float4*>(xb + (size_t)i1 * D_MODEL) + tid);
        float4 a2 = *(reinterpret_cast<const float4*>(xb + (size_t)i2 * D_MODEL) + tid);
        float4 a3 = *(reinterpret_cast<const float4*>(xb + (size_t)i3 * D_MODEL) + tid);
        float4 o;
        o.x = (a0.x + a1.x + a2.x + a3.x) * 0.25f;
        o.y = (a0.y + a1.y + a2.y + a3.y) * 0.25f;
        o.z = (a0.z + a1.z + a2.z + a3.z) * 0.25f;
        o.w = (a0.w + a1.w + a2.w + a3.w) * 0.25f;
        *(reinterpret_cast<float4*>(ob + (size_t)r * D_MODEL) + tid) = o;
    }
}

extern "C" void kernel_launch(void* const* d_in, const int* in_sizes, int n_in,
                              void* d_out, int out_size, void* d_ws, size_t ws_size,
                              hipStream_t stream) {
    const float* x  = (const float*)d_in[0];
    const float* Wq = (const float*)d_in[1];
    const float* bq = (const float*)d_in[2];
    const float* Wk = (const float*)d_in[3];
    const float* bk = (const float*)d_in[4];
    float* out = (float*)d_out;

    // ws layout: [tab 4KB][Wdt 512KB][Qt 1MB][Kt 1MB]
    char* wsb = (char*)d_ws;
    int*    tab  = (int*)wsb;                                            // 4 KB reserved
    double* Wdt  = (double*)(wsb + 4096);                                // 512 KB
    float*  Qt   = (float*)(wsb + 4096 + (size_t)D_MODEL * NOUT * 8);    // 1 MB
    float*  Kt   = Qt + (size_t)NBATCH * 32 * T_SEQ;                     // 1 MB

    wprep_probe<<<dim3(256), dim3(256), 0, stream>>>(Wq, Wk, Wdt, tab);
    proj_mfma<<<dim3(NROWS / 16), dim3(512), 0, stream>>>(x, Wdt, bq, bk, tab, Qt, Kt);
    sim_topk_gather<<<dim3(2048), dim3(256), 0, stream>>>(x, Qt, Kt, out);
}

// Round 5
// 164.697 us; speedup vs baseline: 1.1021x; 1.1021x over previous
//
#include <hip/hip_runtime.h>
#include <math.h>

#define D_MODEL 1024
#define T_SEQ   2048
#define NBATCH  4
#define NROWS   (NBATCH * T_SEQ)          // 8192
#define NOUT    64                        // 32 q + 32 k

#define XLD   1036  // f64-fallback xlds stride (floats)
#define XLDH  1032  // f16 xh/xl stride (halves): 2064 B/row, 16B aligned; word stride
                    // 516 ≡ 4 mod 32 -> A-frag b128 reads spread evenly over 8 bank-quads
                    // (8 lanes/quad = structural minimum, no extra conflict)

// tab int offsets: f64 probe uses [0..768]; f16 probe:
#define T16F   1024   // flag16
#define T16DM  1025   // dm[lane][4]
#define T16DN  1281   // dn[lane][4]

typedef double v4df __attribute__((ext_vector_type(4)));
typedef float  v4f  __attribute__((ext_vector_type(4)));
typedef _Float16 v8hf __attribute__((ext_vector_type(8)));

// ---------- top-4 helpers: total order = (value desc, index asc) ----------
__device__ __forceinline__ bool key_gt(float av, int ai, float bv, int bi) {
    return (av > bv) || (av == bv && ai < bi);
}

__device__ __forceinline__ void cmpswap(float& v0, int& i0, float& v1, int& i1) {
    bool sw = key_gt(v1, i1, v0, i0);
    float nv0 = sw ? v1 : v0, nv1 = sw ? v0 : v1;
    int   ni0 = sw ? i1 : i0, ni1 = sw ? i0 : i1;
    v0 = nv0; v1 = nv1; i0 = ni0; i1 = ni1;
}

__device__ __forceinline__ void merge4(float (&a)[4], int (&ai)[4],
                                       float b0, int j0, float b1, int j1,
                                       float b2, int j2, float b3, int j3) {
    if (!key_gt(a[0], ai[0], b3, j3)) { a[0] = b3; ai[0] = j3; }
    if (!key_gt(a[1], ai[1], b2, j2)) { a[1] = b2; ai[1] = j2; }
    if (!key_gt(a[2], ai[2], b1, j1)) { a[2] = b1; ai[2] = j1; }
    if (!key_gt(a[3], ai[3], b0, j0)) { a[3] = b0; ai[3] = j0; }
    cmpswap(a[0], ai[0], a[2], ai[2]);
    cmpswap(a[1], ai[1], a[3], ai[3]);
    cmpswap(a[0], ai[0], a[1], ai[1]);
    cmpswap(a[2], ai[2], a[3], ai[3]);
}

__device__ __forceinline__ void insert4(float (&tv)[4], int (&tix)[4], float v, int idx) {
    if (v > tv[3]) {
        bool g0 = v > tv[0], g1 = v > tv[1], g2 = v > tv[2];
        float n0 = g0 ? v : tv[0];
        int   m0 = g0 ? idx : tix[0];
        float n1 = g1 ? (g0 ? tv[0] : v) : tv[1];
        int   m1 = g1 ? (g0 ? tix[0] : idx) : tix[1];
        float n2 = g2 ? (g1 ? tv[1] : v) : tv[2];
        int   m2 = g2 ? (g1 ? tix[1] : idx) : tix[2];
        float n3 = g2 ? tv[2] : v;
        int   m3 = g2 ? tix[2] : idx;
        tv[0] = n0; tv[1] = n1; tv[2] = n2; tv[3] = n3;
        tix[0] = m0; tix[1] = m1; tix[2] = m2; tix[3] = m3;
    }
}

// ---------- f64 MFMA layout probe (proven; fallback path) ----------
__device__ void run_probe(int tid, int* __restrict__ tab)
{
    __shared__ double Aref[16][4];
    __shared__ double Bref[4][16];
    __shared__ double Dref[16][16];

    const int lane = tid;
    if (tid < 64) {
        const int m = lane & 15, k = lane >> 4;
        Aref[m][k] = (double)(1 + m * 4 + k);
        Bref[k][m] = (double)(1 + k * 16 + m);
    }
    __syncthreads();
    {
        const int e = tid;
        const int m = e >> 4, n = e & 15;
        double s = 0.0;
        for (int k = 0; k < 4; ++k) s += Aref[m][k] * Bref[k][n];
        Dref[m][n] = s;
    }
    __syncthreads();

    if (tid >= 64) return;

    int found = -1;
    for (int h = 0; h < 16; ++h) {
        if (found >= 0) break;
        const int fa = h & 1, fb = (h >> 1) & 1, fd = h >> 2;
        const int am = fa ? (lane >> 2) : (lane & 15);
        const int ak = fa ? (lane & 3)  : (lane >> 4);
        const int bn = fb ? (lane >> 2) : (lane & 15);
        const int bk = fb ? (lane & 3)  : (lane >> 4);
        v4df c = {0.0, 0.0, 0.0, 0.0};
        c = __builtin_amdgcn_mfma_f64_16x16x4f64(Aref[am][ak], Bref[bk][bn], c, 0, 0, 0);
        bool ok = true;
        #pragma unroll
        for (int i = 0; i < 4; ++i) {
            int dm, dn;
            if (fd == 0)      { dm = 4 * (lane >> 4) + i; dn = lane & 15; }
            else if (fd == 1) { dn = 4 * (lane >> 4) + i; dm = lane & 15; }
            else if (fd == 2) { dm = (lane >> 4) + 4 * i; dn = lane & 15; }
            else              { dn = (lane >> 4) + 4 * i; dm = lane & 15; }
            if (c[i] != Dref[dm][dn]) ok = false;
        }
        if (__all(ok)) found = h;
    }

    const int fa = (found >= 0) ? (found & 1) : 0;
    const int fb = (found >= 0) ? ((found >> 1) & 1) : 0;
    const int fd = (found >= 0) ? (found >> 2) : 0;
    tab[1   + lane] = fa ? (lane >> 2) : (lane & 15);
    tab[65  + lane] = fa ? (lane & 3)  : (lane >> 4);
    tab[129 + lane] = fb ? (lane & 3)  : (lane >> 4);
    tab[193 + lane] = fb ? (lane >> 2) : (lane & 15);
    #pragma unroll
    for (int i = 0; i < 4; ++i) {
        int dm, dn;
        if (fd == 0)      { dm = 4 * (lane >> 4) + i; dn = lane & 15; }
        else if (fd == 1) { dn = 4 * (lane >> 4) + i; dm = lane & 15; }
        else if (fd == 2) { dm = (lane >> 4) + 4 * i; dn = lane & 15; }
        else              { dn = (lane >> 4) + 4 * i; dm = lane & 15; }
        tab[257 + lane * 4 + i] = dm;
        tab[513 + lane * 4 + i] = dn;
    }
    if (lane == 0) tab[0] = found;
}

// ---------- f16 MFMA (16x16x32) layout probe ----------
// Assumes the standard A/B mapping (A: row=lane&15, k=(lane>>4)*8+j; B mirrored);
// probes the two D-layout candidates (m89: C/D dtype-independent). Asymmetric
// exact-integer inputs (<=61, sums <=115K: exact in f16 products / f32 sums).
// found<0 -> f64 fallback used.
__device__ void run_probe16(int tid, int* __restrict__ tab)
{
    __shared__ _Float16 A16[16][32];
    __shared__ _Float16 B16[32][16];
    __shared__ float    D16[16][16];

    for (int e = tid; e < 512; e += 256) {
        const int m = e >> 5, k = e & 31;
        A16[m][k] = (_Float16)(float)(1 + (3 * m + 5 * k) % 61);
        const int kk = e >> 4, n = e & 15;
        B16[kk][n] = (_Float16)(float)(1 + (7 * kk + 11 * n) % 59);
    }
    __syncthreads();
    {
        const int m = tid >> 4, n = tid & 15;
        float s = 0.f;
        for (int k = 0; k < 32; ++k) s += (float)A16[m][k] * (float)B16[k][n];
        D16[m][n] = s;
    }
    __syncthreads();

    if (tid >= 64) return;
    const int lane = tid;

    v8hf a, b;
    const int ab = (lane >> 4) * 8;
    #pragma unroll
    for (int j = 0; j < 8; ++j) {
        a[j] = A16[lane & 15][ab + j];
        b[j] = B16[ab + j][lane & 15];
    }
    v4f c = {0.f, 0.f, 0.f, 0.f};
    c = __builtin_amdgcn_mfma_f32_16x16x32_f16(a, b, c, 0, 0, 0);

    bool ok0 = true, ok1 = true;
    #pragma unroll
    for (int i = 0; i < 4; ++i) {
        ok0 = ok0 && (c[i] == D16[4 * (lane >> 4) + i][lane & 15]);
        ok1 = ok1 && (c[i] == D16[lane & 15][4 * (lane >> 4) + i]);
    }
    int found = __all(ok0) ? 0 : (__all(ok1) ? 1 : -1);
    const int fd = (found == 1) ? 1 : 0;
    #pragma unroll
    for (int i = 0; i < 4; ++i) {
        const int dm = fd ? (lane & 15) : (4 * (lane >> 4) + i);
        const int dn = fd ? (4 * (lane >> 4) + i) : (lane & 15);
        tab[T16DM + lane * 4 + i] = dm;
        tab[T16DN + lane * 4 + i] = dn;
    }
    if (lane == 0) tab[T16F] = found;
}

// ---------- Phase 1: W convert (f64 + f16 split) + probes (block 0) ----------
__global__ __launch_bounds__(256) void wprep_probe(
    const float* __restrict__ Wq, const float* __restrict__ Wk,
    double* __restrict__ Wdt, _Float16* __restrict__ Wh, _Float16* __restrict__ Wl,
    int* __restrict__ tab)
{
    const int tid = threadIdx.x;
    const int idx = blockIdx.x * 256 + tid;   // 65536 total

    {   // f64 transposed layout Wdt[d][64]
        const int o = idx & 63;
        const int d = idx >> 6;
        float v = (o < 32) ? Wq[(size_t)o * D_MODEL + d]
                           : Wk[(size_t)(o - 32) * D_MODEL + d];
        Wdt[(size_t)d * 64 + o] = (double)v;
    }
    {   // f16 split, row layout Wh/Wl[out][d] (coalesced writes)
        const int o = idx >> 10;
        const int d = idx & 1023;
        float v = (o < 32) ? Wq[(size_t)o * D_MODEL + d]
                           : Wk[(size_t)(o - 32) * D_MODEL + d];
        _Float16 h = (_Float16)v;
        Wh[(size_t)o * D_MODEL + d] = h;
        Wl[(size_t)o * D_MODEL + d] = (_Float16)(v - (float)h);
    }

    if (blockIdx.x == 0) {
        run_probe(tid, tab);     // internal barriers: all 256 participate
        run_probe16(tid, tab);
    }
}

// ---------- Phase 2: projection, f16-split MFMA (f64-MFMA / scalar fallback) ----------
// grid 512 (16 rows/block), block 256 (4 waves; wave og owns outs og*16..+15).
// Q = x·W with x=xh+xl, W=wh+wl (f16): acc = hh + hl + lh in three f32 MFMA
// chains over full K=1024 (32 kc, ascending; fixed combine order -> deterministic).
// xl·wl dropped (~2^-22 rel). Round-4 lesson: f64 MFMA measures ~19.6 TF
// effective (4x below spec; chain-splitting null) -> dtype change, not scheduling.
__global__ __launch_bounds__(256) void proj(
    const float* __restrict__ x, const double* __restrict__ Wdt,
    const _Float16* __restrict__ Wh, const _Float16* __restrict__ Wl,
    const float* __restrict__ bq, const float* __restrict__ bk_,
    const int* __restrict__ tab,
    float* __restrict__ Qt, float* __restrict__ Kt)
{
    __shared__ __align__(16) char ldsraw[16 * XLD * 4];   // 66304 B (>= f16 use 66048)

    const int tid  = threadIdx.x;
    const int lane = tid & 63;
    const int wav  = tid >> 6;                                  // 0..3
    const int og   = __builtin_amdgcn_readfirstlane(wav);
    const int row0 = blockIdx.x * 16;

    const int flag16 = tab[T16F];

    if (flag16 >= 0) {
        _Float16* xh = (_Float16*)ldsraw;                 // [16][XLDH]
        _Float16* xl = xh + 16 * XLDH;

        // stage + split: 16 rows x 1024 f32 = 4096 float4, 16/thread, coalesced
        #pragma unroll
        for (int j = 0; j < 16; ++j) {
            const int f  = j * 256 + tid;
            const int r  = f >> 8;
            const int c4 = f & 255;
            float4 v = *reinterpret_cast<const float4*>(
                x + (size_t)(row0 + r) * D_MODEL + c4 * 4);
            union { _Float16 h[4]; short4 s; } uh, ul;
            const float vv[4] = {v.x, v.y, v.z, v.w};
            #pragma unroll
            for (int e = 0; e < 4; ++e) {
                _Float16 h = (_Float16)vv[e];
                uh.h[e] = h;
                ul.h[e] = (_Float16)(vv[e] - (float)h);
            }
            *reinterpret_cast<short4*>(&xh[r * XLDH + c4 * 4]) = uh.s;
            *reinterpret_cast<short4*>(&xl[r * XLDH + c4 * 4]) = ul.s;
        }
        __syncthreads();

        const int am   = lane & 15;
        const int koff = (lane >> 4) * 8;
        const _Float16* bhrow = Wh + (size_t)(og * 16 + am) * D_MODEL + koff;
        const _Float16* blrow = Wl + (size_t)(og * 16 + am) * D_MODEL + koff;
        const _Float16* arow  = &xh[am * XLDH + koff];
        const _Float16* arl   = &xl[am * XLDH + koff];

        v4f hh = {0.f, 0.f, 0.f, 0.f};
        v4f hl = {0.f, 0.f, 0.f, 0.f};
        v4f lh = {0.f, 0.f, 0.f, 0.f};
        #pragma unroll 8
        for (int kc = 0; kc < 32; ++kc) {
            v8hf ah = *reinterpret_cast<const v8hf*>(arow + kc * 32);
            v8hf al = *reinterpret_cast<const v8hf*>(arl  + kc * 32);
            v8hf bh = *reinterpret_cast<const v8hf*>(bhrow + kc * 32);
            v8hf bl = *reinterpret_cast<const v8hf*>(blrow + kc * 32);
            hh = __builtin_amdgcn_mfma_f32_16x16x32_f16(ah, bh, hh, 0, 0, 0);
            hl = __builtin_amdgcn_mfma_f32_16x16x32_f16(ah, bl, hl, 0, 0, 0);
            lh = __builtin_amdgcn_mfma_f32_16x16x32_f16(al, bh, lh, 0, 0, 0);
        }

        #pragma unroll
        for (int i = 0; i < 4; ++i) {
            const float tot = (hh[i] + hl[i]) + lh[i];
            const int dmv = tab[T16DM + lane * 4 + i];
            const int dnv = tab[T16DN + lane * 4 + i];
            const int out = og * 16 + dnv;
            const int row = row0 + dmv;
            const int bb  = row >> 11, t = row & 2047;
            const float bias = (out < 32) ? bq[out] : bk_[out - 32];
            const float v = tot + bias;
            if (out < 32) Qt[((size_t)bb * 32 + out) * T_SEQ + t] = v;
            else          Kt[((size_t)bb * 32 + (out - 32)) * T_SEQ + t] = v;
        }
        return;
    }

    // ---------------- f64 fallback (correct, slower; probe16 failed) ----------------
    float* xlds = (float*)ldsraw;   // [16][XLD]
    #pragma unroll
    for (int j = 0; j < 16; ++j) {
        const int f  = j * 256 + tid;
        const int r  = f >> 8;
        const int c4 = f & 255;
        float4 v = *reinterpret_cast<const float4*>(
            x + (size_t)(row0 + r) * D_MODEL + c4 * 4);
        *reinterpret_cast<float4*>(&xlds[r * XLD + c4 * 4]) = v;
    }
    __syncthreads();

    const int flag = tab[0];
    v4df acc = {0.0, 0.0, 0.0, 0.0};

    if (flag >= 0) {
        const int am  = tab[1   + lane];
        const int ak  = tab[65  + lane];
        const int bkk = tab[129 + lane];
        const int bn  = tab[193 + lane];
        const double* wcol = Wdt + og * 16;
        #pragma unroll 8
        for (int kk = 0; kk < 256; ++kk) {
            double a = (double)xlds[am * XLD + kk * 4 + ak];
            double b = wcol[(size_t)(kk * 4 + bkk) * 64 + bn];
            acc = __builtin_amdgcn_mfma_f64_16x16x4f64(a, b, acc, 0, 0, 0);
        }
        #pragma unroll
        for (int i = 0; i < 4; ++i) {
            const int dmv = tab[257 + lane * 4 + i];
            const int dnv = tab[513 + lane * 4 + i];
            const int out = og * 16 + dnv;
            const int row = row0 + dmv;
            const int bb  = row >> 11, t = row & 2047;
            const double bias = (out < 32) ? (double)bq[out] : (double)bk_[out - 32];
            const float v = (float)(acc[i] + bias);
            if (out < 32) Qt[((size_t)bb * 32 + out) * T_SEQ + t] = v;
            else          Kt[((size_t)bb * 32 + (out - 32)) * T_SEQ + t] = v;
        }
    } else {
        const int n  = lane & 15;
        const int r4 = (lane >> 4) * 4;
        const int out = og * 16 + n;
        const double* wcol = Wdt + out;
        for (int d = 0; d < D_MODEL; ++d) {
            double wv = wcol[(size_t)d * 64];
            #pragma unroll
            for (int i = 0; i < 4; ++i)
                acc[i] = fma((double)xlds[(r4 + i) * XLD + d], wv, acc[i]);
        }
        #pragma unroll
        for (int i = 0; i < 4; ++i) {
            const int row = row0 + r4 + i;
            const int bb  = row >> 11, t = row & 2047;
            const double bias = (out < 32) ? (double)bq[out] : (double)bk_[out - 32];
            const float v = (float)(acc[i] + bias);
            if (out < 32) Qt[((size_t)bb * 32 + out) * T_SEQ + t] = v;
            else          Kt[((size_t)bb * 32 + (out - 32)) * T_SEQ + t] = v;
        }
    }
}

// ---------- Phase 3: sim + top-4 + gather, L2-direct, spill-free ----------
// Round-4 lesson: compiler spilled at VGPR 32/60 with big per-thread state.
// Now r3 geometry (grid 1024, 8 rows/block, micro 4t x 8s) but the 8-s strip
// is processed as TWO sequential 4-s halves: acc[4][4]+tv/tix[4][4] ~ 70 live
// regs -> no spill at ~80-96 VGPR, 16 waves/CU. Insert order per row is still
// s-ascending -> bit-identical top-4 vs all prior rounds.
__global__ __launch_bounds__(256) void sim_topk_gather(
    const float* __restrict__ x,
    const float* __restrict__ Qt, const float* __restrict__ Kt,
    float* __restrict__ out)
{
    __shared__ float cV[4][8][4];
    __shared__ int   cI[4][8][4];
    __shared__ int   topIdx[8][4];

    const int tid  = threadIdx.x;
    const int lane = tid & 63;
    const int wav  = tid >> 6;            // 0..3
    const int tt   = blockIdx.x & 255;
    const int b    = blockIdx.x >> 8;
    const int tblk = tt * 8;
    const int tg   = tid & 1;             // 2 t-groups x 4 rows = 8 rows
    const int sg   = tid >> 1;            // 128 s-groups x 8 s (x2 sweeps) = 2048 s

    const float* QtB = Qt + (size_t)b * 32 * T_SEQ;
    const float* KtB = Kt + (size_t)b * 32 * T_SEQ;
    const int trow0 = tblk + tg * 4;

    float tv[4][4]; int tix[4][4];
    #pragma unroll
    for (int r = 0; r < 4; ++r)
        #pragma unroll
        for (int j = 0; j < 4; ++j) { tv[r][j] = -INFINITY; tix[r][j] = 0x7fffffff; }

    #pragma unroll
    for (int sweep = 0; sweep < 2; ++sweep) {
        #pragma unroll
        for (int half = 0; half < 2; ++half) {
            const int sb = sweep * 1024 + sg * 8 + half * 4;

            float acc[4][4];
            #pragma unroll
            for (int r = 0; r < 4; ++r)
                #pragma unroll
                for (int c = 0; c < 4; ++c) acc[r][c] = 0.f;

            #pragma unroll 8
            for (int i = 0; i < 32; ++i) {
                float4 qv = *reinterpret_cast<const float4*>(QtB + (size_t)i * T_SEQ + trow0);
                float4 kv = *reinterpret_cast<const float4*>(KtB + (size_t)i * T_SEQ + sb);
                const float qa[4] = {qv.x, qv.y, qv.z, qv.w};
                const float ka[4] = {kv.x, kv.y, kv.z, kv.w};
                #pragma unroll
                for (int r = 0; r < 4; ++r)
                    #pragma unroll
                    for (int c = 0; c < 4; ++c)
                        acc[r][c] = fmaf(qa[r], ka[c], acc[r][c]);
            }

            #pragma unroll
            for (int c = 0; c < 4; ++c)
                #pragma unroll
                for (int r = 0; r < 4; ++r)
                    insert4(tv[r], tix[r], acc[r][c], sb + c);
        }
    }

    // in-wave butterfly: masks 2..32 preserve t-group (lane&1)
    #pragma unroll
    for (int m = 2; m <= 32; m <<= 1) {
        #pragma unroll
        for (int r = 0; r < 4; ++r) {
            float b0 = __shfl_xor(tv[r][0], m, 64);
            float b1 = __shfl_xor(tv[r][1], m, 64);
            float b2 = __shfl_xor(tv[r][2], m, 64);
            float b3 = __shfl_xor(tv[r][3], m, 64);
            int   j0 = __shfl_xor(tix[r][0], m, 64);
            int   j1 = __shfl_xor(tix[r][1], m, 64);
            int   j2 = __shfl_xor(tix[r][2], m, 64);
            int   j3 = __shfl_xor(tix[r][3], m, 64);
            merge4(tv[r], tix[r], b0, j0, b1, j1, b2, j2, b3, j3);
        }
    }

    if (lane < 2) {    // lane == tg; rows lane*4+r
        #pragma unroll
        for (int r = 0; r < 4; ++r)
            #pragma unroll
            for (int j = 0; j < 4; ++j) {
                cV[wav][lane * 4 + r][j] = tv[r][j];
                cI[wav][lane * 4 + r][j] = tix[r][j];
            }
    }
    __syncthreads();

    // cross-wave merge (4 waves) -> final top-4 per row (8 rows)
    if (tid < 8) {
        float mv[4]; int mi[4];
        #pragma unroll
        for (int j = 0; j < 4; ++j) { mv[j] = cV[0][tid][j]; mi[j] = cI[0][tid][j]; }
        #pragma unroll
        for (int w = 1; w < 4; ++w)
            merge4(mv, mi,
                   cV[w][tid][0], cI[w][tid][0],
                   cV[w][tid][1], cI[w][tid][1],
                   cV[w][tid][2], cI[w][tid][2],
                   cV[w][tid][3], cI[w][tid][3]);
        #pragma unroll
        for (int j = 0; j < 4; ++j) topIdx[tid][j] = mi[j];
    }
    __syncthreads();

    // gather + mean for this block's 8 rows; 256 threads cover the 1024-float row
    const float* xb = x + (size_t)b * T_SEQ * D_MODEL;
    float* ob = out + ((size_t)b * T_SEQ + tblk) * D_MODEL;
    #pragma unroll 4
    for (int r = 0; r < 8; ++r) {
        const int i0 = topIdx[r][0], i1 = topIdx[r][1], i2 = topIdx[r][2], i3 = topIdx[r][3];
        float4 a0 = *(reinterpret_cast<const float4*>(xb + (size_t)i0 * D_MODEL) + tid);
        float4 a1 = *(reinterpret_cast<const float4*>(xb + (size_t)i1 * D_MODEL) + tid);
        float4 a2 = *(reinterpret_cast<const float4*>(xb + (size_t)i2 * D_MODEL) + tid);
        float4 a3 = *(reinterpret_cast<const float4*>(xb + (size_t)i3 * D_MODEL) + tid);
        float4 o;
        o.x = (a0.x + a1.x + a2.x + a3.x) * 0.25f;
        o.y = (a0.y + a1.y + a2.y + a3.y) * 0.25f;
        o.z = (a0.z + a1.z + a2.z + a3.z) * 0.25f;
        o.w = (a0.w + a1.w + a2.w + a3.w) * 0.25f;
        *(reinterpret_cast<float4*>(ob + (size_t)r * D_MODEL) + tid) = o;
    }
}

extern "C" void kernel_launch(void* const* d_in, const int* in_sizes, int n_in,
                              void* d_out, int out_size, void* d_ws, size_t ws_size,
                              hipStream_t stream) {
    const float* x  = (const float*)d_in[0];
    const float* Wq = (const float*)d_in[1];
    const float* bq = (const float*)d_in[2];
    const float* Wk = (const float*)d_in[3];
    const float* bk = (const float*)d_in[4];
    float* out = (float*)d_out;

    // ws layout: [tab 8KB][Wdt 512KB][Wh 128KB][Wl 128KB][Qt 1MB][Kt 1MB] = ~2.76MB
    char* wsb = (char*)d_ws;
    int*      tab = (int*)wsb;                                   // 8 KB reserved
    double*   Wdt = (double*)(wsb + 8192);                       // 512 KB
    _Float16* Wh  = (_Float16*)(wsb + 8192 + 524288);            // 128 KB
    _Float16* Wl  = (_Float16*)(wsb + 8192 + 524288 + 131072);   // 128 KB
    float*    Qt  = (float*)(wsb + 8192 + 524288 + 262144);      // 1 MB
    float*    Kt  = Qt + (size_t)NBATCH * 32 * T_SEQ;            // 1 MB

    wprep_probe<<<dim3(256), dim3(256), 0, stream>>>(Wq, Wk, Wdt, Wh, Wl, tab);
    proj<<<dim3(NROWS / 16), dim3(256), 0, stream>>>(x, Wdt, Wh, Wl, bq, bk, tab, Qt, Kt);
    sim_topk_gather<<<dim3(1024), dim3(256), 0, stream>>>(x, Qt, Kt, out);
}

// Round 6
// 152.123 us; speedup vs baseline: 1.1932x; 1.0827x over previous
//
#include <hip/hip_runtime.h>
#include <math.h>

#define D_MODEL 1024
#define T_SEQ   2048
#define NBATCH  4
#define NROWS   (NBATCH * T_SEQ)          // 8192
#define NOUT    64                        // 32 q + 32 k

#define XLD   1036  // f64-fallback xlds stride (floats)
#define XLDH  1032  // f16 xh/xl stride (halves)

// tab int offsets: f64 probe uses [0..768]; f16 probe:
#define T16F   1024   // flag16: 0 = expected m89 layout, 1 = transposed D, -1 = fail

typedef double v4df __attribute__((ext_vector_type(4)));
typedef float  v4f  __attribute__((ext_vector_type(4)));
typedef _Float16 v8hf __attribute__((ext_vector_type(8)));

// ---------- top-4 helpers: total order = (value desc, index asc) ----------
__device__ __forceinline__ bool key_gt(float av, int ai, float bv, int bi) {
    return (av > bv) || (av == bv && ai < bi);
}

__device__ __forceinline__ void cmpswap(float& v0, int& i0, float& v1, int& i1) {
    bool sw = key_gt(v1, i1, v0, i0);
    float nv0 = sw ? v1 : v0, nv1 = sw ? v0 : v1;
    int   ni0 = sw ? i1 : i0, ni1 = sw ? i0 : i1;
    v0 = nv0; v1 = nv1; i0 = ni0; i1 = ni1;
}

// merge sorted-desc a[4] with sorted-desc b[4] -> top4 of union into a (bitonic)
__device__ __forceinline__ void merge4(float (&a)[4], int (&ai)[4],
                                       float b0, int j0, float b1, int j1,
                                       float b2, int j2, float b3, int j3) {
    if (!key_gt(a[0], ai[0], b3, j3)) { a[0] = b3; ai[0] = j3; }
    if (!key_gt(a[1], ai[1], b2, j2)) { a[1] = b2; ai[1] = j2; }
    if (!key_gt(a[2], ai[2], b1, j1)) { a[2] = b1; ai[2] = j1; }
    if (!key_gt(a[3], ai[3], b0, j0)) { a[3] = b0; ai[3] = j0; }
    cmpswap(a[0], ai[0], a[2], ai[2]);
    cmpswap(a[1], ai[1], a[3], ai[3]);
    cmpswap(a[0], ai[0], a[1], ai[1]);
    cmpswap(a[2], ai[2], a[3], ai[3]);
}

__device__ __forceinline__ void insert4(float (&tv)[4], int (&tix)[4], float v, int idx) {
    if (v > tv[3]) {
        bool g0 = v > tv[0], g1 = v > tv[1], g2 = v > tv[2];
        float n0 = g0 ? v : tv[0];
        int   m0 = g0 ? idx : tix[0];
        float n1 = g1 ? (g0 ? tv[0] : v) : tv[1];
        int   m1 = g1 ? (g0 ? tix[0] : idx) : tix[1];
        float n2 = g2 ? (g1 ? tv[1] : v) : tv[2];
        int   m2 = g2 ? (g1 ? tix[1] : idx) : tix[2];
        float n3 = g2 ? tv[2] : v;
        int   m3 = g2 ? tix[2] : idx;
        tv[0] = n0; tv[1] = n1; tv[2] = n2; tv[3] = n3;
        tix[0] = m0; tix[1] = m1; tix[2] = m2; tix[3] = m3;
    }
}

// ---------- f64 MFMA layout probe (proven; fallback path) ----------
__device__ void run_probe(int tid, int* __restrict__ tab)
{
    __shared__ double Aref[16][4];
    __shared__ double Bref[4][16];
    __shared__ double Dref[16][16];

    const int lane = tid;
    if (tid < 64) {
        const int m = lane & 15, k = lane >> 4;
        Aref[m][k] = (double)(1 + m * 4 + k);
        Bref[k][m] = (double)(1 + k * 16 + m);
    }
    __syncthreads();
    {
        const int e = tid;
        const int m = e >> 4, n = e & 15;
        double s = 0.0;
        for (int k = 0; k < 4; ++k) s += Aref[m][k] * Bref[k][n];
        Dref[m][n] = s;
    }
    __syncthreads();

    if (tid >= 64) return;

    int found = -1;
    for (int h = 0; h < 16; ++h) {
        if (found >= 0) break;
        const int fa = h & 1, fb = (h >> 1) & 1, fd = h >> 2;
        const int am = fa ? (lane >> 2) : (lane & 15);
        const int ak = fa ? (lane & 3)  : (lane >> 4);
        const int bn = fb ? (lane >> 2) : (lane & 15);
        const int bk = fb ? (lane & 3)  : (lane >> 4);
        v4df c = {0.0, 0.0, 0.0, 0.0};
        c = __builtin_amdgcn_mfma_f64_16x16x4f64(Aref[am][ak], Bref[bk][bn], c, 0, 0, 0);
        bool ok = true;
        #pragma unroll
        for (int i = 0; i < 4; ++i) {
            int dm, dn;
            if (fd == 0)      { dm = 4 * (lane >> 4) + i; dn = lane & 15; }
            else if (fd == 1) { dn = 4 * (lane >> 4) + i; dm = lane & 15; }
            else if (fd == 2) { dm = (lane >> 4) + 4 * i; dn = lane & 15; }
            else              { dn = (lane >> 4) + 4 * i; dm = lane & 15; }
            if (c[i] != Dref[dm][dn]) ok = false;
        }
        if (__all(ok)) found = h;
    }

    const int fa = (found >= 0) ? (found & 1) : 0;
    const int fb = (found >= 0) ? ((found >> 1) & 1) : 0;
    const int fd = (found >= 0) ? (found >> 2) : 0;
    tab[1   + lane] = fa ? (lane >> 2) : (lane & 15);
    tab[65  + lane] = fa ? (lane & 3)  : (lane >> 4);
    tab[129 + lane] = fb ? (lane & 3)  : (lane >> 4);
    tab[193 + lane] = fb ? (lane >> 2) : (lane & 15);
    #pragma unroll
    for (int i = 0; i < 4; ++i) {
        int dm, dn;
        if (fd == 0)      { dm = 4 * (lane >> 4) + i; dn = lane & 15; }
        else if (fd == 1) { dn = 4 * (lane >> 4) + i; dm = lane & 15; }
        else if (fd == 2) { dm = (lane >> 4) + 4 * i; dn = lane & 15; }
        else              { dn = (lane >> 4) + 4 * i; dm = lane & 15; }
        tab[257 + lane * 4 + i] = dm;
        tab[513 + lane * 4 + i] = dn;
    }
    if (lane == 0) tab[0] = found;
}

// ---------- f16 MFMA (16x16x32) layout probe ----------
// Verifies A/B mapping (A: row=lane&15, k=(lane>>4)*8+j; B mirrored) and D
// layout. flag16==0 -> m89 layout (c[i] at row 4*(lane>>4)+i, col lane&15).
// Exact-integer asymmetric inputs; products exact in f32 inside MFMA.
__device__ void run_probe16(int tid, int* __restrict__ tab)
{
    __shared__ _Float16 A16[16][32];
    __shared__ _Float16 B16[32][16];
    __shared__ float    D16[16][16];

    for (int e = tid; e < 512; e += 256) {
        const int m = e >> 5, k = e & 31;
        A16[m][k] = (_Float16)(float)(1 + (3 * m + 5 * k) % 61);
        const int kk = e >> 4, n = e & 15;
        B16[kk][n] = (_Float16)(float)(1 + (7 * kk + 11 * n) % 59);
    }
    __syncthreads();
    {
        const int m = tid >> 4, n = tid & 15;
        float s = 0.f;
        for (int k = 0; k < 32; ++k) s += (float)A16[m][k] * (float)B16[k][n];
        D16[m][n] = s;
    }
    __syncthreads();

    if (tid >= 64) return;
    const int lane = tid;

    v8hf a, b;
    const int ab = (lane >> 4) * 8;
    #pragma unroll
    for (int j = 0; j < 8; ++j) {
        a[j] = A16[lane & 15][ab + j];
        b[j] = B16[ab + j][lane & 15];
    }
    v4f c = {0.f, 0.f, 0.f, 0.f};
    c = __builtin_amdgcn_mfma_f32_16x16x32_f16(a, b, c, 0, 0, 0);

    bool ok0 = true, ok1 = true;
    #pragma unroll
    for (int i = 0; i < 4; ++i) {
        ok0 = ok0 && (c[i] == D16[4 * (lane >> 4) + i][lane & 15]);
        ok1 = ok1 && (c[i] == D16[lane & 15][4 * (lane >> 4) + i]);
    }
    int found = __all(ok0) ? 0 : (__all(ok1) ? 1 : -1);
    if (lane == 0) tab[T16F] = found;
}

// ---------- Phase 1: W convert (f64 + f16 split) + probes (block 0) ----------
__global__ __launch_bounds__(256) void wprep_probe(
    const float* __restrict__ Wq, const float* __restrict__ Wk,
    double* __restrict__ Wdt, _Float16* __restrict__ Wh, _Float16* __restrict__ Wl,
    int* __restrict__ tab)
{
    const int tid = threadIdx.x;
    const int idx = blockIdx.x * 256 + tid;   // 65536 total

    {   // f64 transposed layout Wdt[d][64]
        const int o = idx & 63;
        const int d = idx >> 6;
        float v = (o < 32) ? Wq[(size_t)o * D_MODEL + d]
                           : Wk[(size_t)(o - 32) * D_MODEL + d];
        Wdt[(size_t)d * 64 + o] = (double)v;
    }
    {   // f16 split, row layout Wh/Wl[out][d] (coalesced writes)
        const int o = idx >> 10;
        const int d = idx & 1023;
        float v = (o < 32) ? Wq[(size_t)o * D_MODEL + d]
                           : Wk[(size_t)(o - 32) * D_MODEL + d];
        _Float16 h = (_Float16)v;
        Wh[(size_t)o * D_MODEL + d] = h;
        Wl[(size_t)o * D_MODEL + d] = (_Float16)(v - (float)h);
    }

    if (blockIdx.x == 0) {
        run_probe(tid, tab);     // internal barriers: all 256 participate
        run_probe16(tid, tab);
    }
}

// ---------- Phase 2: projection ----------
// flag16==0: f16-split MFMA (hh+hl+lh), writes f16-split projections
// Qh/Ql/Kh/Kl in [global_row][32] layout (feeds the MFMA sim directly).
// else: proven f64-MFMA / scalar fallback writing f32 Qt/Kt [b][32][t].
__global__ __launch_bounds__(256) void proj(
    const float* __restrict__ x, const double* __restrict__ Wdt,
    const _Float16* __restrict__ Wh, const _Float16* __restrict__ Wl,
    const float* __restrict__ bq, const float* __restrict__ bk_,
    const int* __restrict__ tab,
    float* __restrict__ Qt, float* __restrict__ Kt,
    _Float16* __restrict__ Qh, _Float16* __restrict__ Ql,
    _Float16* __restrict__ Kh, _Float16* __restrict__ Kl)
{
    __shared__ __align__(16) char ldsraw[16 * XLD * 4];   // 66304 B

    const int tid  = threadIdx.x;
    const int lane = tid & 63;
    const int wav  = tid >> 6;                                  // 0..3
    const int og   = __builtin_amdgcn_readfirstlane(wav);
    const int row0 = blockIdx.x * 16;

    const int flag16 = tab[T16F];

    if (flag16 == 0) {
        _Float16* xh = (_Float16*)ldsraw;                 // [16][XLDH]
        _Float16* xl = xh + 16 * XLDH;

        #pragma unroll
        for (int j = 0; j < 16; ++j) {
            const int f  = j * 256 + tid;
            const int r  = f >> 8;
            const int c4 = f & 255;
            float4 v = *reinterpret_cast<const float4*>(
                x + (size_t)(row0 + r) * D_MODEL + c4 * 4);
            union { _Float16 h[4]; short4 s; } uh, ul;
            const float vv[4] = {v.x, v.y, v.z, v.w};
            #pragma unroll
            for (int e = 0; e < 4; ++e) {
                _Float16 h = (_Float16)vv[e];
                uh.h[e] = h;
                ul.h[e] = (_Float16)(vv[e] - (float)h);
            }
            *reinterpret_cast<short4*>(&xh[r * XLDH + c4 * 4]) = uh.s;
            *reinterpret_cast<short4*>(&xl[r * XLDH + c4 * 4]) = ul.s;
        }
        __syncthreads();

        const int am   = lane & 15;
        const int koff = (lane >> 4) * 8;
        const _Float16* bhrow = Wh + (size_t)(og * 16 + am) * D_MODEL + koff;
        const _Float16* blrow = Wl + (size_t)(og * 16 + am) * D_MODEL + koff;
        const _Float16* arow  = &xh[am * XLDH + koff];
        const _Float16* arl   = &xl[am * XLDH + koff];

        v4f hh = {0.f, 0.f, 0.f, 0.f};
        v4f hl = {0.f, 0.f, 0.f, 0.f};
        v4f lh = {0.f, 0.f, 0.f, 0.f};
        #pragma unroll 8
        for (int kc = 0; kc < 32; ++kc) {
            v8hf ah = *reinterpret_cast<const v8hf*>(arow + kc * 32);
            v8hf al = *reinterpret_cast<const v8hf*>(arl  + kc * 32);
            v8hf bh = *reinterpret_cast<const v8hf*>(bhrow + kc * 32);
            v8hf bl = *reinterpret_cast<const v8hf*>(blrow + kc * 32);
            hh = __builtin_amdgcn_mfma_f32_16x16x32_f16(ah, bh, hh, 0, 0, 0);
            hl = __builtin_amdgcn_mfma_f32_16x16x32_f16(ah, bl, hl, 0, 0, 0);
            lh = __builtin_amdgcn_mfma_f32_16x16x32_f16(al, bh, lh, 0, 0, 0);
        }

        #pragma unroll
        for (int i = 0; i < 4; ++i) {
            const float tot = (hh[i] + hl[i]) + lh[i];
            const int dmv = 4 * (lane >> 4) + i;   // flag16==0 (m89) D layout
            const int dnv = lane & 15;
            const int o   = og * 16 + dnv;
            const int row = row0 + dmv;            // global row 0..8191
            const float bias = (o < 32) ? bq[o] : bk_[o - 32];
            const float v = tot + bias;
            const _Float16 h = (_Float16)v;
            const _Float16 l = (_Float16)(v - (float)h);
            if (o < 32) {
                Qh[(size_t)row * 32 + o] = h;
                Ql[(size_t)row * 32 + o] = l;
            } else {
                Kh[(size_t)row * 32 + (o - 32)] = h;
                Kl[(size_t)row * 32 + (o - 32)] = l;
            }
        }
        return;
    }

    // ---------------- f64 fallback (correct, slower) ----------------
    float* xlds = (float*)ldsraw;   // [16][XLD]
    #pragma unroll
    for (int j = 0; j < 16; ++j) {
        const int f  = j * 256 + tid;
        const int r  = f >> 8;
        const int c4 = f & 255;
        float4 v = *reinterpret_cast<const float4*>(
            x + (size_t)(row0 + r) * D_MODEL + c4 * 4);
        *reinterpret_cast<float4*>(&xlds[r * XLD + c4 * 4]) = v;
    }
    __syncthreads();

    const int flag = tab[0];
    v4df acc = {0.0, 0.0, 0.0, 0.0};

    if (flag >= 0) {
        const int am  = tab[1   + lane];
        const int ak  = tab[65  + lane];
        const int bkk = tab[129 + lane];
        const int bn  = tab[193 + lane];
        const double* wcol = Wdt + og * 16;
        #pragma unroll 8
        for (int kk = 0; kk < 256; ++kk) {
            double a = (double)xlds[am * XLD + kk * 4 + ak];
            double b = wcol[(size_t)(kk * 4 + bkk) * 64 + bn];
            acc = __builtin_amdgcn_mfma_f64_16x16x4f64(a, b, acc, 0, 0, 0);
        }
        #pragma unroll
        for (int i = 0; i < 4; ++i) {
            const int dmv = tab[257 + lane * 4 + i];
            const int dnv = tab[513 + lane * 4 + i];
            const int o   = og * 16 + dnv;
            const int row = row0 + dmv;
            const int bb  = row >> 11, t = row & 2047;
            const double bias = (o < 32) ? (double)bq[o] : (double)bk_[o - 32];
            const float v = (float)(acc[i] + bias);
            if (o < 32) Qt[((size_t)bb * 32 + o) * T_SEQ + t] = v;
            else        Kt[((size_t)bb * 32 + (o - 32)) * T_SEQ + t] = v;
        }
    } else {
        const int n  = lane & 15;
        const int r4 = (lane >> 4) * 4;
        const int o  = og * 16 + n;
        const double* wcol = Wdt + o;
        for (int d = 0; d < D_MODEL; ++d) {
            double wv = wcol[(size_t)d * 64];
            #pragma unroll
            for (int i = 0; i < 4; ++i)
                acc[i] = fma((double)xlds[(r4 + i) * XLD + d], wv, acc[i]);
        }
        #pragma unroll
        for (int i = 0; i < 4; ++i) {
            const int row = row0 + r4 + i;
            const int bb  = row >> 11, t = row & 2047;
            const double bias = (o < 32) ? (double)bq[o] : (double)bk_[o - 32];
            const float v = (float)(acc[i] + bias);
            if (o < 32) Qt[((size_t)bb * 32 + o) * T_SEQ + t] = v;
            else        Kt[((size_t)bb * 32 + (o - 32)) * T_SEQ + t] = v;
        }
    }
}

// ---------- Phase 3: MFMA sim + top-4 + gather ----------
// grid 512 = b(4) x ttile(128 x 16 rows); block 256 (4 waves, wave w owns
// s-quarter w*512). K=32 fits ONE 16x16x32 MFMA: per 16x16 sim tile, 4 chained
// MFMAs (hh,hl,lh,ll) -> exact (q_h+q_l)(k_h+k_l) under f32 accum; split error
// ~1.4e-7 rel, same regime the top-4 margins already tolerated (r5 proj).
// Lane holds rows 4*(lane>>4)+i, col s0+(lane&15) (m89 layout, probed).
// Butterfly masks 1..8 merge the 16 cols/group; LDS merges 4 s-quarters.
// Round-5 lesson: f32-FMA sim was stuck 55-78us across all reg shapes; MFMA
// cuts VALU ~8x and leaves the kernel gather-bound (~15us HBM floor).
__global__ __launch_bounds__(256) void sim_topk_gather(
    const float* __restrict__ x,
    const _Float16* __restrict__ Qh, const _Float16* __restrict__ Ql,
    const _Float16* __restrict__ Kh, const _Float16* __restrict__ Kl,
    const float* __restrict__ Qt, const float* __restrict__ Kt,
    const int* __restrict__ tab,
    float* __restrict__ out)
{
    __shared__ float sV[16][16][4];
    __shared__ int   sI[16][16][4];
    __shared__ int   topIdx[16][4];

    const int tid  = threadIdx.x;
    const int lane = tid & 63;
    const int wav  = tid >> 6;            // 0..3
    const int tt   = blockIdx.x & 127;
    const int b    = blockIdx.x >> 7;
    const int row0g = b * T_SEQ + tt * 16;   // global row base

    if (tab[T16F] == 0) {
        const int m  = lane & 15;
        const int ko = (lane >> 4) * 8;
        v8hf ah = *reinterpret_cast<const v8hf*>(Qh + (size_t)(row0g + m) * 32 + ko);
        v8hf al = *reinterpret_cast<const v8hf*>(Ql + (size_t)(row0g + m) * 32 + ko);
        const _Float16* KhB = Kh + (size_t)b * T_SEQ * 32;
        const _Float16* KlB = Kl + (size_t)b * T_SEQ * 32;

        float tv[4][4]; int tix[4][4];
        #pragma unroll
        for (int r = 0; r < 4; ++r)
            #pragma unroll
            for (int j = 0; j < 4; ++j) { tv[r][j] = -INFINITY; tix[r][j] = 0x7fffffff; }

        const int sq = wav * 512;
        #pragma unroll 4
        for (int st = 0; st < 32; ++st) {
            const int s0 = sq + st * 16;
            v8hf bh = *reinterpret_cast<const v8hf*>(KhB + (size_t)(s0 + m) * 32 + ko);
            v8hf bl = *reinterpret_cast<const v8hf*>(KlB + (size_t)(s0 + m) * 32 + ko);
            v4f c = {0.f, 0.f, 0.f, 0.f};
            c = __builtin_amdgcn_mfma_f32_16x16x32_f16(ah, bh, c, 0, 0, 0);
            c = __builtin_amdgcn_mfma_f32_16x16x32_f16(ah, bl, c, 0, 0, 0);
            c = __builtin_amdgcn_mfma_f32_16x16x32_f16(al, bh, c, 0, 0, 0);
            c = __builtin_amdgcn_mfma_f32_16x16x32_f16(al, bl, c, 0, 0, 0);
            const int col = s0 + m;
            #pragma unroll
            for (int i = 0; i < 4; ++i) insert4(tv[i], tix[i], c[i], col);
        }

        // butterfly masks 1,2,4,8: lanes within a 16-group share the same 4 rows
        #pragma unroll
        for (int mk = 1; mk <= 8; mk <<= 1) {
            #pragma unroll
            for (int r = 0; r < 4; ++r) {
                float b0 = __shfl_xor(tv[r][0], mk, 64);
                float b1 = __shfl_xor(tv[r][1], mk, 64);
                float b2 = __shfl_xor(tv[r][2], mk, 64);
                float b3 = __shfl_xor(tv[r][3], mk, 64);
                int   j0 = __shfl_xor(tix[r][0], mk, 64);
                int   j1 = __shfl_xor(tix[r][1], mk, 64);
                int   j2 = __shfl_xor(tix[r][2], mk, 64);
                int   j3 = __shfl_xor(tix[r][3], mk, 64);
                merge4(tv[r], tix[r], b0, j0, b1, j1, b2, j2, b3, j3);
            }
        }

        if ((lane & 15) == 0) {
            const int rbase = (lane >> 4) * 4;
            #pragma unroll
            for (int r = 0; r < 4; ++r)
                #pragma unroll
                for (int j = 0; j < 4; ++j) {
                    sV[wav][rbase + r][j] = tv[r][j];
                    sI[wav][rbase + r][j] = tix[r][j];
                }
        }
        __syncthreads();

        if (tid < 16) {
            float mv[4]; int mi[4];
            #pragma unroll
            for (int j = 0; j < 4; ++j) { mv[j] = sV[0][tid][j]; mi[j] = sI[0][tid][j]; }
            #pragma unroll
            for (int w = 1; w < 4; ++w)
                merge4(mv, mi,
                       sV[w][tid][0], sI[w][tid][0],
                       sV[w][tid][1], sI[w][tid][1],
                       sV[w][tid][2], sI[w][tid][2],
                       sV[w][tid][3], sI[w][tid][3]);
            #pragma unroll
            for (int j = 0; j < 4; ++j) topIdx[tid][j] = mi[j];
        }
        __syncthreads();
    } else {
        // ---- f32 fallback from Qt/Kt (bit-identical ordering to prior rounds) ----
        const float* QtB = Qt + (size_t)b * 32 * T_SEQ;
        const float* KtB = Kt + (size_t)b * 32 * T_SEQ;
        const int row   = tid >> 4;        // 0..15
        const int chunk = tid & 15;        // 16 chunks x 128 s
        const int trow  = tt * 16 + row;
        float q[32];
        #pragma unroll 8
        for (int i = 0; i < 32; ++i) q[i] = QtB[(size_t)i * T_SEQ + trow];
        float tv4[4]; int tix4[4];
        #pragma unroll
        for (int j = 0; j < 4; ++j) { tv4[j] = -INFINITY; tix4[j] = 0x7fffffff; }
        const int sbeg = chunk * 128;
        for (int s = sbeg; s < sbeg + 128; ++s) {
            float sum = 0.f;
            #pragma unroll 8
            for (int i = 0; i < 32; ++i)
                sum = fmaf(q[i], KtB[(size_t)i * T_SEQ + s], sum);
            insert4(tv4, tix4, sum, s);
        }
        #pragma unroll
        for (int j = 0; j < 4; ++j) { sV[row][chunk][j] = tv4[j]; sI[row][chunk][j] = tix4[j]; }
        __syncthreads();
        if (tid < 16) {
            float mv[4]; int mi[4];
            #pragma unroll
            for (int j = 0; j < 4; ++j) { mv[j] = sV[tid][0][j]; mi[j] = sI[tid][0][j]; }
            #pragma unroll
            for (int cc = 1; cc < 16; ++cc)
                merge4(mv, mi,
                       sV[tid][cc][0], sI[tid][cc][0],
                       sV[tid][cc][1], sI[tid][cc][1],
                       sV[tid][cc][2], sI[tid][cc][2],
                       sV[tid][cc][3], sI[tid][cc][3]);
            #pragma unroll
            for (int j = 0; j < 4; ++j) topIdx[tid][j] = mi[j];
        }
        __syncthreads();
    }

    // gather + mean for this block's 16 rows; 256 threads cover the 1024-f row
    const float* xb = x + (size_t)b * T_SEQ * D_MODEL;
    float* ob = out + (size_t)row0g * D_MODEL;
    #pragma unroll 2
    for (int r = 0; r < 16; ++r) {
        const int i0 = topIdx[r][0], i1 = topIdx[r][1], i2 = topIdx[r][2], i3 = topIdx[r][3];
        float4 a0 = *(reinterpret_cast<const float4*>(xb + (size_t)i0 * D_MODEL) + tid);
        float4 a1 = *(reinterpret_cast<const float4*>(xb + (size_t)i1 * D_MODEL) + tid);
        float4 a2 = *(reinterpret_cast<const float4*>(xb + (size_t)i2 * D_MODEL) + tid);
        float4 a3 = *(reinterpret_cast<const float4*>(xb + (size_t)i3 * D_MODEL) + tid);
        float4 o;
        o.x = (a0.x + a1.x + a2.x + a3.x) * 0.25f;
        o.y = (a0.y + a1.y + a2.y + a3.y) * 0.25f;
        o.z = (a0.z + a1.z + a2.z + a3.z) * 0.25f;
        o.w = (a0.w + a1.w + a2.w + a3.w) * 0.25f;
        *(reinterpret_cast<float4*>(ob + (size_t)r * D_MODEL) + tid) = o;
    }
}

extern "C" void kernel_launch(void* const* d_in, const int* in_sizes, int n_in,
                              void* d_out, int out_size, void* d_ws, size_t ws_size,
                              hipStream_t stream) {
    const float* x  = (const float*)d_in[0];
    const float* Wq = (const float*)d_in[1];
    const float* bq = (const float*)d_in[2];
    const float* Wk = (const float*)d_in[3];
    const float* bk = (const float*)d_in[4];
    float* out = (float*)d_out;

    // ws: [tab 8K][Wdt 512K][Wh 128K][Wl 128K][Qt 1M][Kt 1M][Qh 512K][Ql 512K][Kh 512K][Kl 512K]
    char* wsb = (char*)d_ws;
    int*      tab = (int*)wsb;
    double*   Wdt = (double*)(wsb + 8192);
    _Float16* Wh  = (_Float16*)(wsb + 8192 + 524288);
    _Float16* Wl  = (_Float16*)(wsb + 8192 + 524288 + 131072);
    float*    Qt  = (float*)(wsb + 8192 + 524288 + 262144);
    float*    Kt  = Qt + (size_t)NBATCH * 32 * T_SEQ;
    _Float16* Qh  = (_Float16*)((char*)Kt + (size_t)NBATCH * 32 * T_SEQ * 4);
    _Float16* Ql  = Qh + (size_t)NROWS * 32;
    _Float16* Kh  = Ql + (size_t)NROWS * 32;
    _Float16* Kl  = Kh + (size_t)NROWS * 32;

    wprep_probe<<<dim3(256), dim3(256), 0, stream>>>(Wq, Wk, Wdt, Wh, Wl, tab);
    proj<<<dim3(NROWS / 16), dim3(256), 0, stream>>>(x, Wdt, Wh, Wl, bq, bk, tab,
                                                     Qt, Kt, Qh, Ql, Kh, Kl);
    sim_topk_gather<<<dim3(512), dim3(256), 0, stream>>>(x, Qh, Ql, Kh, Kl, Qt, Kt, tab, out);
}

// Round 7
// 151.571 us; speedup vs baseline: 1.1976x; 1.0036x over previous
//
#include <hip/hip_runtime.h>
#include <math.h>

#define D_MODEL 1024
#define T_SEQ   2048
#define NBATCH  4
#define NROWS   (NBATCH * T_SEQ)          // 8192
#define NOUT    64                        // 32 q + 32 k

// tab int offsets
#define T16F   1024   // flag16: 0 = expected m89 layout, else fallback

typedef float  v4f  __attribute__((ext_vector_type(4)));
typedef _Float16 v8hf __attribute__((ext_vector_type(8)));

// ---------- top-4 helpers: total order = (value desc, index asc) ----------
__device__ __forceinline__ bool key_gt(float av, int ai, float bv, int bi) {
    return (av > bv) || (av == bv && ai < bi);
}

__device__ __forceinline__ void cmpswap(float& v0, int& i0, float& v1, int& i1) {
    bool sw = key_gt(v1, i1, v0, i0);
    float nv0 = sw ? v1 : v0, nv1 = sw ? v0 : v1;
    int   ni0 = sw ? i1 : i0, ni1 = sw ? i0 : i1;
    v0 = nv0; v1 = nv1; i0 = ni0; i1 = ni1;
}

// merge sorted-desc a[4] with sorted-desc b[4] -> top4 of union into a (bitonic)
__device__ __forceinline__ void merge4(float (&a)[4], int (&ai)[4],
                                       float b0, int j0, float b1, int j1,
                                       float b2, int j2, float b3, int j3) {
    if (!key_gt(a[0], ai[0], b3, j3)) { a[0] = b3; ai[0] = j3; }
    if (!key_gt(a[1], ai[1], b2, j2)) { a[1] = b2; ai[1] = j2; }
    if (!key_gt(a[2], ai[2], b1, j1)) { a[2] = b1; ai[2] = j1; }
    if (!key_gt(a[3], ai[3], b0, j0)) { a[3] = b0; ai[3] = j0; }
    cmpswap(a[0], ai[0], a[2], ai[2]);
    cmpswap(a[1], ai[1], a[3], ai[3]);
    cmpswap(a[0], ai[0], a[1], ai[1]);
    cmpswap(a[2], ai[2], a[3], ai[3]);
}

__device__ __forceinline__ void insert4(float (&tv)[4], int (&tix)[4], float v, int idx) {
    if (v > tv[3]) {
        bool g0 = v > tv[0], g1 = v > tv[1], g2 = v > tv[2];
        float n0 = g0 ? v : tv[0];
        int   m0 = g0 ? idx : tix[0];
        float n1 = g1 ? (g0 ? tv[0] : v) : tv[1];
        int   m1 = g1 ? (g0 ? tix[0] : idx) : tix[1];
        float n2 = g2 ? (g1 ? tv[1] : v) : tv[2];
        int   m2 = g2 ? (g1 ? tix[1] : idx) : tix[2];
        float n3 = g2 ? tv[2] : v;
        int   m3 = g2 ? tix[2] : idx;
        tv[0] = n0; tv[1] = n1; tv[2] = n2; tv[3] = n3;
        tix[0] = m0; tix[1] = m1; tix[2] = m2; tix[3] = m3;
    }
}

// ---------- f16 MFMA (16x16x32) layout probe ----------
// Verifies A/B mapping (A: row=lane&15, k=(lane>>4)*8+j; B mirrored) and the
// m89 D layout (c[i] at row 4*(lane>>4)+i, col lane&15). Exact-integer
// asymmetric inputs. flag16 != 0 -> scalar f64 fallback everywhere.
__device__ void run_probe16(int tid, int* __restrict__ tab)
{
    __shared__ _Float16 A16[16][32];
    __shared__ _Float16 B16[32][16];
    __shared__ float    D16[16][16];

    for (int e = tid; e < 512; e += 256) {
        const int m = e >> 5, k = e & 31;
        A16[m][k] = (_Float16)(float)(1 + (3 * m + 5 * k) % 61);
        const int kk = e >> 4, n = e & 15;
        B16[kk][n] = (_Float16)(float)(1 + (7 * kk + 11 * n) % 59);
    }
    __syncthreads();
    {
        const int m = tid >> 4, n = tid & 15;
        float s = 0.f;
        for (int k = 0; k < 32; ++k) s += (float)A16[m][k] * (float)B16[k][n];
        D16[m][n] = s;
    }
    __syncthreads();

    if (tid >= 64) return;
    const int lane = tid;

    v8hf a, b;
    const int ab = (lane >> 4) * 8;
    #pragma unroll
    for (int j = 0; j < 8; ++j) {
        a[j] = A16[lane & 15][ab + j];
        b[j] = B16[ab + j][lane & 15];
    }
    v4f c = {0.f, 0.f, 0.f, 0.f};
    c = __builtin_amdgcn_mfma_f32_16x16x32_f16(a, b, c, 0, 0, 0);

    bool ok0 = true;
    #pragma unroll
    for (int i = 0; i < 4; ++i)
        ok0 = ok0 && (c[i] == D16[4 * (lane >> 4) + i][lane & 15]);
    if (lane == 0) tab[T16F] = __all(ok0) ? 0 : -1;
}

// ---------- Phase 1: W convert (f64 transposed + f16 split) + probe ----------
__global__ __launch_bounds__(256) void wprep_probe(
    const float* __restrict__ Wq, const float* __restrict__ Wk,
    double* __restrict__ Wdt, _Float16* __restrict__ Wh, _Float16* __restrict__ Wl,
    int* __restrict__ tab)
{
    const int tid = threadIdx.x;
    const int idx = blockIdx.x * 256 + tid;   // 65536 total

    {   // f64 transposed layout Wdt[d][64] (scalar fallback)
        const int o = idx & 63;
        const int d = idx >> 6;
        float v = (o < 32) ? Wq[(size_t)o * D_MODEL + d]
                           : Wk[(size_t)(o - 32) * D_MODEL + d];
        Wdt[(size_t)d * 64 + o] = (double)v;
    }
    {   // f16 split, row layout Wh/Wl[out][d] (coalesced writes)
        const int o = idx >> 10;
        const int d = idx & 1023;
        float v = (o < 32) ? Wq[(size_t)o * D_MODEL + d]
                           : Wk[(size_t)(o - 32) * D_MODEL + d];
        _Float16 h = (_Float16)v;
        Wh[(size_t)o * D_MODEL + d] = h;
        Wl[(size_t)o * D_MODEL + d] = (_Float16)(v - (float)h);
    }

    if (blockIdx.x == 0) run_probe16(tid, tab);
}

// ---------- Phase 2: projection, LDS-free, 8-wave K-split ----------
// grid 512 (16 rows/block), block 512 (8 waves). Wave (og = wav>>1, half = wav&1):
// og owns outs og*16..+15; half owns K in [half*512, +512) -> 16-long MFMA chains.
// Round-6 lesson: 66KB LDS staging + 32-long chains at 8 waves/CU kept proj
// ~50us (latency-bound). Now: direct global x reads (f16 split in regs; x
// re-read 8x ~= 256MB of L2 traffic ~7us), 4KB LDS for the half-combine,
// 16 waves/CU. Fixed combine order -> deterministic.
__global__ __launch_bounds__(512) void proj(
    const float* __restrict__ x, const double* __restrict__ Wdt,
    const _Float16* __restrict__ Wh, const _Float16* __restrict__ Wl,
    const float* __restrict__ bq, const float* __restrict__ bk_,
    const int* __restrict__ tab,
    float* __restrict__ Qt, float* __restrict__ Kt,
    _Float16* __restrict__ Qh, _Float16* __restrict__ Ql,
    _Float16* __restrict__ Kh, _Float16* __restrict__ Kl)
{
    __shared__ float  comb[4][64][4];     // 4 KB (f16 path)
    __shared__ double combd[4][64][4];    // 8 KB (fallback)

    const int tid  = threadIdx.x;
    const int lane = tid & 63;
    const int wav  = tid >> 6;                                    // 0..7
    const int og   = __builtin_amdgcn_readfirstlane(wav >> 1);    // 0..3
    const int half = __builtin_amdgcn_readfirstlane(wav & 1);     // 0..1
    const int row0 = blockIdx.x * 16;
    const int kb   = half * 512;

    if (tab[T16F] == 0) {
        const int m  = lane & 15;
        const int ko = (lane >> 4) * 8;
        const float*    xrow  = x  + (size_t)(row0 + m) * D_MODEL + kb + ko;
        const _Float16* whrow = Wh + (size_t)(og * 16 + m) * D_MODEL + kb + ko;
        const _Float16* wlrow = Wl + (size_t)(og * 16 + m) * D_MODEL + kb + ko;

        v4f hh = {0.f, 0.f, 0.f, 0.f};
        v4f hl = {0.f, 0.f, 0.f, 0.f};
        v4f lh = {0.f, 0.f, 0.f, 0.f};
        #pragma unroll 4
        for (int kc = 0; kc < 16; ++kc) {
            float4 x0 = *reinterpret_cast<const float4*>(xrow + kc * 32);
            float4 x1 = *reinterpret_cast<const float4*>(xrow + kc * 32 + 4);
            const float f[8] = {x0.x, x0.y, x0.z, x0.w, x1.x, x1.y, x1.z, x1.w};
            v8hf ah, al;
            #pragma unroll
            for (int e = 0; e < 8; ++e) {
                _Float16 h = (_Float16)f[e];
                ah[e] = h;
                al[e] = (_Float16)(f[e] - (float)h);
            }
            v8hf bh = *reinterpret_cast<const v8hf*>(whrow + kc * 32);
            v8hf bl = *reinterpret_cast<const v8hf*>(wlrow + kc * 32);
            hh = __builtin_amdgcn_mfma_f32_16x16x32_f16(ah, bh, hh, 0, 0, 0);
            hl = __builtin_amdgcn_mfma_f32_16x16x32_f16(ah, bl, hl, 0, 0, 0);
            lh = __builtin_amdgcn_mfma_f32_16x16x32_f16(al, bh, lh, 0, 0, 0);
        }

        v4f tot;
        #pragma unroll
        for (int i = 0; i < 4; ++i) tot[i] = (hh[i] + hl[i]) + lh[i];

        if (half == 1) {
            #pragma unroll
            for (int i = 0; i < 4; ++i) comb[og][lane][i] = tot[i];
        }
        __syncthreads();
        if (half == 0) {
            #pragma unroll
            for (int i = 0; i < 4; ++i) {
                const float t = tot[i] + comb[og][lane][i];   // fixed order
                const int dmv = 4 * (lane >> 4) + i;           // m89 D layout
                const int o   = og * 16 + m;
                const int row = row0 + dmv;
                const float bias = (o < 32) ? bq[o] : bk_[o - 32];
                const float v = t + bias;
                const _Float16 h = (_Float16)v;
                const _Float16 l = (_Float16)(v - (float)h);
                if (o < 32) {
                    Qh[(size_t)row * 32 + o] = h;
                    Ql[(size_t)row * 32 + o] = l;
                } else {
                    Kh[(size_t)row * 32 + (o - 32)] = h;
                    Kl[(size_t)row * 32 + (o - 32)] = l;
                }
            }
        }
        return;
    }

    // ---------------- scalar f64 fallback (probe16 failed) ----------------
    {
        const int n  = lane & 15;
        const int r4 = (lane >> 4) * 4;
        const int o  = og * 16 + n;
        const double* wcol = Wdt + o;
        double acc[4] = {0.0, 0.0, 0.0, 0.0};
        for (int dd = 0; dd < 512; ++dd) {
            const int d = kb + dd;
            double wv = wcol[(size_t)d * 64];
            #pragma unroll
            for (int i = 0; i < 4; ++i)
                acc[i] = fma((double)x[(size_t)(row0 + r4 + i) * D_MODEL + d], wv, acc[i]);
        }
        if (half == 1) {
            #pragma unroll
            for (int i = 0; i < 4; ++i) combd[og][lane][i] = acc[i];
        }
        __syncthreads();
        if (half == 0) {
            #pragma unroll
            for (int i = 0; i < 4; ++i) {
                const double t = acc[i] + combd[og][lane][i];  // fixed order
                const int row = row0 + r4 + i;
                const int bb  = row >> 11, tt = row & 2047;
                const double bias = (o < 32) ? (double)bq[o] : (double)bk_[o - 32];
                const float v = (float)(t + bias);
                if (o < 32) Qt[((size_t)bb * 32 + o) * T_SEQ + tt] = v;
                else        Kt[((size_t)bb * 32 + (o - 32)) * T_SEQ + tt] = v;
            }
        }
    }
}

// ---------- Phase 3: MFMA sim + top-4 + gather, 8-wave s-split ----------
// grid 512 = b(4) x ttile(128 x 16 rows); block 512 (8 waves, wave w owns
// s-range w*256, 16 st iterations) -> 16 waves/CU (round-6: 8, occupancy 18%).
// Top-4-of-union under the strict (desc value, asc idx) total order is
// partition-invariant -> result identical to round-6. Gather: 512 thr, 2 rows
// per pass. Fallback (flag16!=0): f32 chunk-scalar from Qt/Kt.
__global__ __launch_bounds__(512) void sim_topk_gather(
    const float* __restrict__ x,
    const _Float16* __restrict__ Qh, const _Float16* __restrict__ Ql,
    const _Float16* __restrict__ Kh, const _Float16* __restrict__ Kl,
    const float* __restrict__ Qt, const float* __restrict__ Kt,
    const int* __restrict__ tab,
    float* __restrict__ out)
{
    __shared__ float sV[8][16][4];
    __shared__ int   sI[8][16][4];
    __shared__ float sVf[16][32][4];
    __shared__ int   sIf[16][32][4];
    __shared__ int   topIdx[16][4];

    const int tid  = threadIdx.x;
    const int lane = tid & 63;
    const int wav  = tid >> 6;            // 0..7
    const int tt   = blockIdx.x & 127;
    const int b    = blockIdx.x >> 7;
    const int row0g = b * T_SEQ + tt * 16;   // global row base

    if (tab[T16F] == 0) {
        const int m  = lane & 15;
        const int ko = (lane >> 4) * 8;
        v8hf ah = *reinterpret_cast<const v8hf*>(Qh + (size_t)(row0g + m) * 32 + ko);
        v8hf al = *reinterpret_cast<const v8hf*>(Ql + (size_t)(row0g + m) * 32 + ko);
        const _Float16* KhB = Kh + (size_t)b * T_SEQ * 32;
        const _Float16* KlB = Kl + (size_t)b * T_SEQ * 32;

        float tv[4][4]; int tix[4][4];
        #pragma unroll
        for (int r = 0; r < 4; ++r)
            #pragma unroll
            for (int j = 0; j < 4; ++j) { tv[r][j] = -INFINITY; tix[r][j] = 0x7fffffff; }

        const int sq = wav * 256;
        #pragma unroll 4
        for (int st = 0; st < 16; ++st) {
            const int s0 = sq + st * 16;
            v8hf bh = *reinterpret_cast<const v8hf*>(KhB + (size_t)(s0 + m) * 32 + ko);
            v8hf bl = *reinterpret_cast<const v8hf*>(KlB + (size_t)(s0 + m) * 32 + ko);
            v4f c = {0.f, 0.f, 0.f, 0.f};
            c = __builtin_amdgcn_mfma_f32_16x16x32_f16(ah, bh, c, 0, 0, 0);
            c = __builtin_amdgcn_mfma_f32_16x16x32_f16(ah, bl, c, 0, 0, 0);
            c = __builtin_amdgcn_mfma_f32_16x16x32_f16(al, bh, c, 0, 0, 0);
            c = __builtin_amdgcn_mfma_f32_16x16x32_f16(al, bl, c, 0, 0, 0);
            const int col = s0 + m;
            #pragma unroll
            for (int i = 0; i < 4; ++i) insert4(tv[i], tix[i], c[i], col);
        }

        // butterfly masks 1,2,4,8: merge the 16 cols within each lane-group
        #pragma unroll
        for (int mk = 1; mk <= 8; mk <<= 1) {
            #pragma unroll
            for (int r = 0; r < 4; ++r) {
                float b0 = __shfl_xor(tv[r][0], mk, 64);
                float b1 = __shfl_xor(tv[r][1], mk, 64);
                float b2 = __shfl_xor(tv[r][2], mk, 64);
                float b3 = __shfl_xor(tv[r][3], mk, 64);
                int   j0 = __shfl_xor(tix[r][0], mk, 64);
                int   j1 = __shfl_xor(tix[r][1], mk, 64);
                int   j2 = __shfl_xor(tix[r][2], mk, 64);
                int   j3 = __shfl_xor(tix[r][3], mk, 64);
                merge4(tv[r], tix[r], b0, j0, b1, j1, b2, j2, b3, j3);
            }
        }

        if ((lane & 15) == 0) {
            const int rbase = (lane >> 4) * 4;
            #pragma unroll
            for (int r = 0; r < 4; ++r)
                #pragma unroll
                for (int j = 0; j < 4; ++j) {
                    sV[wav][rbase + r][j] = tv[r][j];
                    sI[wav][rbase + r][j] = tix[r][j];
                }
        }
        __syncthreads();

        if (tid < 16) {
            float mv[4]; int mi[4];
            #pragma unroll
            for (int j = 0; j < 4; ++j) { mv[j] = sV[0][tid][j]; mi[j] = sI[0][tid][j]; }
            #pragma unroll
            for (int w = 1; w < 8; ++w)
                merge4(mv, mi,
                       sV[w][tid][0], sI[w][tid][0],
                       sV[w][tid][1], sI[w][tid][1],
                       sV[w][tid][2], sI[w][tid][2],
                       sV[w][tid][3], sI[w][tid][3]);
            #pragma unroll
            for (int j = 0; j < 4; ++j) topIdx[tid][j] = mi[j];
        }
        __syncthreads();
    } else {
        // ---- f32 fallback from Qt/Kt ----
        const float* QtB = Qt + (size_t)b * 32 * T_SEQ;
        const float* KtB = Kt + (size_t)b * 32 * T_SEQ;
        const int row   = tid >> 5;        // 0..15
        const int chunk = tid & 31;        // 32 chunks x 64 s
        const int trow  = tt * 16 + row;
        float q[32];
        #pragma unroll 8
        for (int i = 0; i < 32; ++i) q[i] = QtB[(size_t)i * T_SEQ + trow];
        float tv4[4]; int tix4[4];
        #pragma unroll
        for (int j = 0; j < 4; ++j) { tv4[j] = -INFINITY; tix4[j] = 0x7fffffff; }
        const int sbeg = chunk * 64;
        for (int s = sbeg; s < sbeg + 64; ++s) {
            float sum = 0.f;
            #pragma unroll 8
            for (int i = 0; i < 32; ++i)
                sum = fmaf(q[i], KtB[(size_t)i * T_SEQ + s], sum);
            insert4(tv4, tix4, sum, s);
        }
        #pragma unroll
        for (int j = 0; j < 4; ++j) { sVf[row][chunk][j] = tv4[j]; sIf[row][chunk][j] = tix4[j]; }
        __syncthreads();
        if (tid < 16) {
            float mv[4]; int mi[4];
            #pragma unroll
            for (int j = 0; j < 4; ++j) { mv[j] = sVf[tid][0][j]; mi[j] = sIf[tid][0][j]; }
            for (int cc = 1; cc < 32; ++cc)
                merge4(mv, mi,
                       sVf[tid][cc][0], sIf[tid][cc][0],
                       sVf[tid][cc][1], sIf[tid][cc][1],
                       sVf[tid][cc][2], sIf[tid][cc][2],
                       sVf[tid][cc][3], sIf[tid][cc][3]);
            #pragma unroll
            for (int j = 0; j < 4; ++j) topIdx[tid][j] = mi[j];
        }
        __syncthreads();
    }

    // gather + mean: 512 threads, 2 rows per pass (each row = 256 float4)
    const float* xb = x + (size_t)b * T_SEQ * D_MODEL;
    float* ob = out + (size_t)row0g * D_MODEL;
    const int rh = tid >> 8;     // 0..1
    const int t4 = tid & 255;    // float4 column
    #pragma unroll 2
    for (int rp = 0; rp < 8; ++rp) {
        const int r = rp * 2 + rh;
        const int i0 = topIdx[r][0], i1 = topIdx[r][1], i2 = topIdx[r][2], i3 = topIdx[r][3];
        float4 a0 = *(reinterpret_cast<const float4*>(xb + (size_t)i0 * D_MODEL) + t4);
        float4 a1 = *(reinterpret_cast<const float4*>(xb + (size_t)i1 * D_MODEL) + t4);
        float4 a2 = *(reinterpret_cast<const float4*>(xb + (size_t)i2 * D_MODEL) + t4);
        float4 a3 = *(reinterpret_cast<const float4*>(xb + (size_t)i3 * D_MODEL) + t4);
        float4 o;
        o.x = (a0.x + a1.x + a2.x + a3.x) * 0.25f;
        o.y = (a0.y + a1.y + a2.y + a3.y) * 0.25f;
        o.z = (a0.z + a1.z + a2.z + a3.z) * 0.25f;
        o.w = (a0.w + a1.w + a2.w + a3.w) * 0.25f;
        *(reinterpret_cast<float4*>(ob + (size_t)r * D_MODEL) + t4) = o;
    }
}

extern "C" void kernel_launch(void* const* d_in, const int* in_sizes, int n_in,
                              void* d_out, int out_size, void* d_ws, size_t ws_size,
                              hipStream_t stream) {
    const float* x  = (const float*)d_in[0];
    const float* Wq = (const float*)d_in[1];
    const float* bq = (const float*)d_in[2];
    const float* Wk = (const float*)d_in[3];
    const float* bk = (const float*)d_in[4];
    float* out = (float*)d_out;

    // ws: [tab 8K][Wdt 512K][Wh 128K][Wl 128K][Qt 1M][Kt 1M][Qh 512K][Ql 512K][Kh 512K][Kl 512K]
    char* wsb = (char*)d_ws;
    int*      tab = (int*)wsb;
    double*   Wdt = (double*)(wsb + 8192);
    _Float16* Wh  = (_Float16*)(wsb + 8192 + 524288);
    _Float16* Wl  = (_Float16*)(wsb + 8192 + 524288 + 131072);
    float*    Qt  = (float*)(wsb + 8192 + 524288 + 262144);
    float*    Kt  = Qt + (size_t)NBATCH * 32 * T_SEQ;
    _Float16* Qh  = (_Float16*)((char*)Kt + (size_t)NBATCH * 32 * T_SEQ * 4);
    _Float16* Ql  = Qh + (size_t)NROWS * 32;
    _Float16* Kh  = Ql + (size_t)NROWS * 32;
    _Float16* Kl  = Kh + (size_t)NROWS * 32;

    wprep_probe<<<dim3(256), dim3(256), 0, stream>>>(Wq, Wk, Wdt, Wh, Wl, tab);
    proj<<<dim3(NROWS / 16), dim3(512), 0, stream>>>(x, Wdt, Wh, Wl, bq, bk, tab,
                                                     Qt, Kt, Qh, Ql, Kh, Kl);
    sim_topk_gather<<<dim3(512), dim3(512), 0, stream>>>(x, Qh, Ql, Kh, Kl, Qt, Kt, tab, out);
}